// Round 15
// baseline (203.604 us; speedup 1.0000x reference)
//
#include <hip/hip_runtime.h>
#include <hip/hip_bf16.h>

// Sparse GAT layer — SINGLE fused kernel, PLAIN launch (R14 post-mortem:
// hipLaunchCooperativeKernel is not graph-capturable -> silent no-op ->
// zero output). Grid-wide ordering via a software spin barrier:
//   - residency by construction: 71 KB LDS -> 2 blocks/CU; launch_bounds
//     (512,4) caps VGPR<=128 -> 2 blocks/CU; grid 512 = 256 CU x 2. All
//     blocks co-resident; arrive-before-wait -> no deadlock.
//   - bar[0] (sort arrivals, NC) / bar[1] (gemm arrivals, NG), zeroed by
//     hipMemsetAsync (capture-safe; workspace is re-poisoned each run).
//   - release atomicAdd after __syncthreads (drains block stores to L2,
//     then wbl2 at agent scope); acquire spin load (inv) on the consumer
//     side — cross-XCD visibility per the gfx950 memory model.
// Phase bodies are VERBATIM R13 (passed at 137.2 us):
//   Phase 1a (blocks 0..NC): chunk sort in LDS, CH=16384, desc=ex|(cnt<<15).
//   Phase 1b (blocks NC..NC+NG): bf16 MFMA gemm h=X@W, 128-row tiles,
//     s1/s2 fused epilogue.
//   Phase 2 (all blocks, stride NB buckets): phase A (runs->elist->dlist)
//     waits only on bar[0] — overlaps the gemm tail; phase B (s2/h gather,
//     16 edges/iter flat batch, fast ELU, rowsum-div) waits on bar[1].

constexpr int D    = 128;
constexpr int CH   = 16384;  // edges per sort chunk (64 KB LDS stage)
constexpr int CAPB = 1280;   // per-bucket elist capacity (mean 883, 13 sigma)

typedef __attribute__((ext_vector_type(8))) short bf16x8;   // 8 bf16 = 4 VGPRs
typedef __attribute__((ext_vector_type(4))) float f32x4;

__device__ __forceinline__ short f2bf(float f) {
    unsigned u = __float_as_uint(f);
    unsigned r = (u + 0x7fffu + ((u >> 16) & 1u)) >> 16;    // RNE
    return (short)r;
}
__device__ __forceinline__ float bf2f(short b) {
    return __uint_as_float(((unsigned)(unsigned short)b) << 16);
}
__device__ __forceinline__ short2 pk_bf16(float x, float y) {  // packed RNE cvt
    __hip_bfloat162 bb = __float22bfloat162_rn(make_float2(x, y));
    short2 r;
    __builtin_memcpy(&r, &bb, 4);
    return r;
}

__global__ __launch_bounds__(512, 4) void gat_fused(
    const float* __restrict__ X, const float* __restrict__ W,
    const float* __restrict__ a,
    const int* __restrict__ src, const int* __restrict__ dst,
    int* __restrict__ desc, int* __restrict__ binned,
    short* __restrict__ h, float* __restrict__ s1, float* __restrict__ s2,
    float* __restrict__ out, int* __restrict__ bar,
    int NB, int NC, int NG, int N, int E) {
    __shared__ int sbuf[CH];        // 64 KB: sort stage / gemm lbw / elist
    __shared__ int hist[784];       // sort counters / rdesc+scn overlay
    __shared__ int sarr[1024];      // sort scan / ncnt+exclp+pcnt+ss1 overlay
    const int bid = blockIdx.x, tid = threadIdx.x;

    // ================= PHASE 1 =================
    if (bid < NC) {   // --- chunk-sort path (R13 verbatim) ---
        const int c = bid, t = tid;
        for (int u = t; u < NB; u += 512) hist[u] = 0;
        __syncthreads();
        const int lo = c * CH, hi = min(lo + CH, E);
        const int len = hi - lo;
        const int hi4 = lo + (len & ~3);
        for (int i = lo + t * 4; i < hi4; i += 2048) {
            const int4 s4 = *(const int4*)(src + i);
            atomicAdd(&hist[s4.x >> 6], 1);
            atomicAdd(&hist[s4.y >> 6], 1);
            atomicAdd(&hist[s4.z >> 6], 1);
            atomicAdd(&hist[s4.w >> 6], 1);
        }
        for (int i = hi4 + t; i < hi; i += 512)
            atomicAdd(&hist[src[i] >> 6], 1);
        __syncthreads();
        for (int u = t; u < 1024; u += 512) sarr[u] = (u < NB) ? hist[u] : 0;
        __syncthreads();
        for (int o = 1; o < 1024; o <<= 1) {
            int v[2];
#pragma unroll
            for (int k = 0; k < 2; ++k) {
                const int idx = t + k * 512;
                v[k] = (idx >= o) ? sarr[idx - o] : 0;
            }
            __syncthreads();
#pragma unroll
            for (int k = 0; k < 2; ++k) sarr[t + k * 512] += v[k];
            __syncthreads();
        }
        // 15-bit offset field: ex in [0,16384], cnt in high bits.
        for (int u = t; u < NB; u += 512) {
            const int ex = sarr[u] - hist[u];
            desc[(size_t)c * NB + u] = ex | (hist[u] << 15);
            sarr[u] = ex;
            hist[u] = 0;
        }
        __syncthreads();
        for (int i = lo + t * 4; i < hi4; i += 2048) {
            const int4 s4 = *(const int4*)(src + i);
            const int4 d4 = *(const int4*)(dst + i);
            const int sv[4] = {s4.x, s4.y, s4.z, s4.w};
            const int dv[4] = {d4.x, d4.y, d4.z, d4.w};
#pragma unroll
            for (int j = 0; j < 4; ++j) {
                const int b = sv[j] >> 6;
                const int r = atomicAdd(&hist[b], 1);
                sbuf[sarr[b] + r] = ((sv[j] & 63) << 16) | dv[j];
            }
        }
        for (int i = hi4 + t; i < hi; i += 512) {
            const int s = src[i];
            const int b = s >> 6;
            const int r = atomicAdd(&hist[b], 1);
            sbuf[sarr[b] + r] = ((s & 63) << 16) | dst[i];
        }
        __syncthreads();
        const int len4 = len & ~3;
        for (int i = t * 4; i < len4; i += 2048)
            *(int4*)(binned + (size_t)c * CH + i) = *(const int4*)(sbuf + i);
        for (int i = len4 + t; i < len; i += 512)
            binned[(size_t)c * CH + i] = sbuf[i];
        __syncthreads();   // drain all waves' stores (vmcnt 0) before release
        if (tid == 0)
            __hip_atomic_fetch_add(&bar[0], 1, __ATOMIC_RELEASE,
                                   __HIP_MEMORY_SCOPE_AGENT);
    } else if (bid < NC + NG) {   // --- gemm path (R13 verbatim) ---
        short* lbw = (short*)sbuf;
        for (int f4 = tid; f4 < 4096; f4 += 512) {
            const float4 w4 = *(const float4*)(W + f4 * 4);
            const float wv[4] = {w4.x, w4.y, w4.z, w4.w};
            const int f0 = f4 * 4;
#pragma unroll
            for (int u = 0; u < 4; ++u) {
                const int f = f0 + u;
                const int k = f >> 7, n = f & 127;
                const int sl = ((k >> 5) * 8 + (n >> 4)) * 64 +
                               ((k >> 3) & 3) * 16 + (n & 15);
                lbw[sl * 8 + (k & 7)] = f2bf(wv[u]);
            }
        }
        __syncthreads();
        const int wave = tid >> 6, lane = tid & 63;
        const int r0 = (bid - NC) * 128 + wave * 16;
        const int m = lane & 15, q = lane >> 4;
        const int arow = r0 + m;
        const bool rowok = arow < N;
        const float* xp = X + (size_t)arow * D + q * 8;

        f32x4 acc[8] = {};
#pragma unroll
        for (int s = 0; s < 4; ++s) {
            float4 xa = {0, 0, 0, 0}, xb = {0, 0, 0, 0};
            if (rowok) {
                xa = *(const float4*)(xp + s * 32);
                xb = *(const float4*)(xp + s * 32 + 4);
            }
            bf16x8 af;
            short2 c0 = pk_bf16(xa.x, xa.y), c1 = pk_bf16(xa.z, xa.w);
            short2 c2 = pk_bf16(xb.x, xb.y), c3 = pk_bf16(xb.z, xb.w);
            af[0] = c0.x; af[1] = c0.y; af[2] = c1.x; af[3] = c1.y;
            af[4] = c2.x; af[5] = c2.y; af[6] = c3.x; af[7] = c3.y;
#pragma unroll
            for (int t = 0; t < 8; ++t) {
                bf16x8 bf = *(const bf16x8*)(lbw + ((s * 8 + t) * 64 + lane) * 8);
                acc[t] = __builtin_amdgcn_mfma_f32_16x16x32_bf16(af, bf, acc[t], 0, 0, 0);
            }
        }
        float a1v[8], a2v[8];
#pragma unroll
        for (int t = 0; t < 8; ++t) {
            a1v[t] = a[t * 16 + m];
            a2v[t] = a[D + t * 16 + m];
        }
        // C layout: col = t*16 + (lane&15), row = r0 + (lane>>4)*4 + i
        float p1[4] = {0, 0, 0, 0}, p2[4] = {0, 0, 0, 0};
#pragma unroll
        for (int t = 0; t < 8; ++t) {
            short2 h01 = pk_bf16(acc[t][0], acc[t][1]);
            short2 h23 = pk_bf16(acc[t][2], acc[t][3]);
            const short hb[4] = {h01.x, h01.y, h23.x, h23.y};
#pragma unroll
            for (int i = 0; i < 4; ++i) {
                const int row = r0 + q * 4 + i;
                if (row < N) h[(size_t)row * D + t * 16 + m] = hb[i];
                const float hr = bf2f(hb[i]);
                p1[i] += hr * a1v[t];
                p2[i] += hr * a2v[t];
            }
        }
#pragma unroll
        for (int off = 1; off < 16; off <<= 1) {
#pragma unroll
            for (int i = 0; i < 4; ++i) {
                p1[i] += __shfl_xor(p1[i], off);
                p2[i] += __shfl_xor(p2[i], off);
            }
        }
        if (m < 4) {
            const int row = r0 + q * 4 + m;
            if (row < N) {
                const float v1 = (m == 0) ? p1[0] : (m == 1) ? p1[1] : (m == 2) ? p1[2] : p1[3];
                const float v2 = (m == 0) ? p2[0] : (m == 1) ? p2[1] : (m == 2) ? p2[2] : p2[3];
                s1[row] = v1;
                s2[row] = v2;
            }
        }
        __syncthreads();   // drain all waves' stores before release
        if (tid == 0)
            __hip_atomic_fetch_add(&bar[1], 1, __ATOMIC_RELEASE,
                                   __HIP_MEMORY_SCOPE_AGENT);
    }

    // ===== wait: sort output (binned/desc) readable — phase A only =====
    if (tid == 0) {
        while (__hip_atomic_load(&bar[0], __ATOMIC_ACQUIRE,
                                 __HIP_MEMORY_SCOPE_AGENT) < NC)
            __builtin_amdgcn_s_sleep(16);
    }
    __syncthreads();

    // ================= PHASE 2: aggregate (R13 verbatim, LDS overlaid) ====
    int* elist = sbuf;                                        // CAPB ints
    unsigned short* dlist = (unsigned short*)(sbuf + CAPB);   // CAPB+16 u16
    int* rdesc = hist;                                        // 64
    int* scn   = hist + 128;                                  // 64
    int* ncnt  = sarr;                                        // 64
    int* exclp = sarr + 64;                                   // 64
    int* pcnt  = sarr + 128;                                  // 64
    float* ss1 = (float*)(sarr + 192);                        // 64

    bool gemm_ready = false;
    for (int b = bid; b < NB; b += gridDim.x) {
        __syncthreads();   // previous bucket's phase B done before re-init
        const int n0 = b * 64;
        if (tid < 64) {
            ncnt[tid] = 0;
            pcnt[tid] = 0;
            const int dsc = (tid < NC) ? desc[(size_t)tid * NB + b] : 0;
            rdesc[tid] = dsc;
            int v = dsc >> 15;
#pragma unroll
            for (int o = 1; o < 64; o <<= 1) {
                const int u = __shfl_up(v, o);
                if (tid >= o) v += u;
            }
            scn[tid] = v;   // inclusive
        }
        __syncthreads();
        const int total = scn[63];
        const int nE = min(total, CAPB);
        {   // 16-lane-group run copy (avg run ~21 edges)
            const int gid = tid >> 4, l16 = tid & 15;   // 32 groups x 16
            for (int c = gid; c < NC; c += 32) {
                const int dsc = rdesc[c];
                const int off = dsc & 0x7FFF;
                const int cnt = dsc >> 15;
                const int p0 = scn[c] - cnt;
                for (int j = l16; j < cnt; j += 16) {
                    const int p = p0 + j;
                    if (p < CAPB) elist[p] = binned[(size_t)c * CH + off + j];
                }
            }
        }
        __syncthreads();
        for (int i = tid; i < nE; i += 512) atomicAdd(&ncnt[elist[i] >> 16], 1);
        __syncthreads();
        if (tid < 64) {   // wave 0: 64-wide inclusive shfl-scan -> exclusive
            int v = ncnt[tid];
#pragma unroll
            for (int o = 1; o < 64; o <<= 1) {
                const int u = __shfl_up(v, o);
                if (tid >= o) v += u;
            }
            exclp[tid] = v - ncnt[tid];
        }
        __syncthreads();
        const int tot2 = exclp[63] + ncnt[63];
        if (tid < 16) dlist[tot2 + tid] = 0;      // zero pad (unclamped reads)
        for (int i = tid; i < nE; i += 512) {
            const int e = elist[i];
            const int r = e >> 16;
            const int k = atomicAdd(&pcnt[r], 1);
            dlist[exclp[r] + k] = (unsigned short)(e & 0xFFFF);
        }
        __syncthreads();

        // ===== wait: gemm output (h/s1/s2) readable — once, block-uniform ==
        if (!gemm_ready) {
            if (tid == 0) {
                while (__hip_atomic_load(&bar[1], __ATOMIC_ACQUIRE,
                                         __HIP_MEMORY_SCOPE_AGENT) < NG)
                    __builtin_amdgcn_s_sleep(16);
            }
            __syncthreads();
            gemm_ready = true;
        }
        if (tid < 64) ss1[tid] = (n0 + tid < N) ? s1[n0 + tid] : 0.f;
        __syncthreads();

        // Phase B: wave wid handles nodes r = wid*8 .. wid*8+7.
        const int wid = tid >> 6, lane = tid & 63;
        const int g = lane >> 4, m = lane & 15;
        const int m8 = m * 8;
#pragma unroll 1
        for (int t = 0; t < 8; ++t) {
            const int r = wid * 8 + t;
            const int n = n0 + r;
            if (n >= N) continue;              // wave-uniform
            const int cnt = ncnt[r];
            if (cnt == 0) continue;            // wave-uniform (self-loop => >=1)
            const int beg = exclp[r];
            const float s1n = ss1[r];

            float acc[8] = {};
            float rs = 0.f;
#pragma unroll 1
            for (int k0 = 0; k0 < cnt; k0 += 16) {
                const int dA = dlist[beg + k0 + g];
                const int dB = dlist[beg + k0 + 4 + g];
                const int dC = dlist[beg + k0 + 8 + g];
                const int dD = dlist[beg + k0 + 12 + g];
                const float sA = s2[dA], sB = s2[dB], sC = s2[dC], sD = s2[dD];
                const bf16x8 rA = *(const bf16x8*)(h + (dA << 7) + m8);
                const bf16x8 rB = *(const bf16x8*)(h + (dB << 7) + m8);
                const bf16x8 rC = *(const bf16x8*)(h + (dC << 7) + m8);
                const bf16x8 rD = *(const bf16x8*)(h + (dD << 7) + m8);

                float xA = s1n + sA; xA = xA > 0.f ? xA : 0.2f * xA;
                float eA = __expf(xA);
                if (k0 + g >= cnt) eA = 0.f;
                float xB = s1n + sB; xB = xB > 0.f ? xB : 0.2f * xB;
                float eB = __expf(xB);
                if (k0 + 4 + g >= cnt) eB = 0.f;
                float xC = s1n + sC; xC = xC > 0.f ? xC : 0.2f * xC;
                float eC = __expf(xC);
                if (k0 + 8 + g >= cnt) eC = 0.f;
                float xD = s1n + sD; xD = xD > 0.f ? xD : 0.2f * xD;
                float eD = __expf(xD);
                if (k0 + 12 + g >= cnt) eD = 0.f;
#pragma unroll
                for (int j = 0; j < 8; ++j)
                    acc[j] += eA * bf2f(rA[j]) + eB * bf2f(rB[j]) +
                              eC * bf2f(rC[j]) + eD * bf2f(rD[j]);
                rs += (eA + eB) + (eC + eD);
            }
#pragma unroll
            for (int off = 16; off <= 32; off <<= 1) {
                rs += __shfl_xor(rs, off);
#pragma unroll
                for (int j = 0; j < 8; ++j) acc[j] += __shfl_xor(acc[j], off);
            }
            if (g == 0) {
                const float inv = 1.f / rs;   // self-loop => rs > 0
                float o[8];
#pragma unroll
                for (int j = 0; j < 8; ++j) {
                    const float v = acc[j] * inv;
                    o[j] = v > 0.f ? v : __expf(v) - 1.f;   // fast ELU
                }
                float* op = out + (size_t)n * D + m8;
                *(float4*)op       = make_float4(o[0], o[1], o[2], o[3]);
                *(float4*)(op + 4) = make_float4(o[4], o[5], o[6], o[7]);
            }
        }
    }
}

extern "C" void kernel_launch(void* const* d_in, const int* in_sizes, int n_in,
                              void* d_out, int out_size, void* d_ws, size_t ws_size,
                              hipStream_t stream) {
    const float* X    = (const float*)d_in[0];
    const int*   edge = (const int*)d_in[1];   // [2, E] int32
    const float* W    = (const float*)d_in[2];
    const float* a    = (const float*)d_in[3];
    float* out = (float*)d_out;

    int N = in_sizes[0] / D;
    int E = in_sizes[1] / 2;
    const int* src = edge;
    const int* dst = edge + E;

    int NB = (N + 63) / 64;            // 782 buckets of 64 nodes
    int NC = (E + CH - 1) / CH;        // 43 sort chunks
    int NG = (N + 127) / 128;          // 391 gemm tiles

    // workspace layout (16B-aligned slabs): ~16 MB total
    char* ws = (char*)d_ws;
    short* h    = (short*)ws; ws += (size_t)N * D * sizeof(short);      // 12.8 MB
    int* binned = (int*)ws;   ws += (size_t)NC * CH * sizeof(int);      // 2.8 MB
    int* desc   = (int*)ws;   ws += (size_t)NC * NB * sizeof(int);      // 134 KB
    float* s1   = (float*)ws; ws += (size_t)N * sizeof(float);
    float* s2   = (float*)ws; ws += (size_t)N * sizeof(float);
    int* bar    = (int*)ws;   ws += 4 * sizeof(int);

    hipMemsetAsync(bar, 0, 2 * sizeof(int), stream);   // capture-safe
    gat_fused<<<512, 512, 0, stream>>>(X, W, a, src, dst, desc, binned,
                                       h, s1, s2, out, bar,
                                       NB, NC, NG, N, E);
}